// Round 1
// 1205.071 us; speedup vs baseline: 1.1459x; 1.1459x over previous
//
#include <hip/hip_runtime.h>
#include <math.h>

typedef unsigned short u16;
typedef __attribute__((ext_vector_type(4))) float f32x4;
typedef __attribute__((ext_vector_type(8))) __bf16 bf16x8;
typedef __attribute__((ext_vector_type(8))) u16 u16x8;
typedef __attribute__((ext_vector_type(4))) u16 u16x4;

#define D_MODEL 4096
#define NQKV    12288
#define BL      2048
#define L_SEQ   1024
#define NH      32
#define DH      128

__device__ __forceinline__ u16 f2bf(float f) {
    union { float f; unsigned u; } v; v.f = f;
    unsigned r = (v.u + 0x7fffu + ((v.u >> 16) & 1u)) >> 16;
    return (u16)r;
}
__device__ __forceinline__ float bf2f(u16 b) {
    union { unsigned u; float f; } v; v.u = ((unsigned)b) << 16;
    return v.f;
}
__device__ __forceinline__ void gload_lds16(const void* g, void* l) {
    __builtin_amdgcn_global_load_lds((const __attribute__((address_space(1))) void*)g,
                                     (__attribute__((address_space(3))) void*)l, 16, 0, 0);
}
__device__ __forceinline__ f32x4 mfma_bf16(bf16x8 a, bf16x8 b, f32x4 c) {
    return __builtin_amdgcn_mfma_f32_16x16x32_bf16(a, b, c, 0, 0, 0);
}

// raw barrier (no implicit vmcnt(0) drain) + compiler memory fence
#define BAR()      asm volatile("s_barrier" ::: "memory")
#define WAIT_VM4() asm volatile("s_waitcnt vmcnt(4)" ::: "memory")
#define WAIT_VM0() asm volatile("s_waitcnt vmcnt(0)" ::: "memory")

// ---------------- fp32 -> bf16 convert (hidden states) ----------------
__global__ __launch_bounds__(256) void convert_f32_bf16(const float* __restrict__ in,
                                                        u16* __restrict__ out, int n4) {
    int i = blockIdx.x * 256 + threadIdx.x;
    if (i < n4) {
        float4 v = ((const float4*)in)[i];
        u16x4 o;
        o[0] = f2bf(v.x); o[1] = f2bf(v.y); o[2] = f2bf(v.z); o[3] = f2bf(v.w);
        ((u16x4*)out)[i] = o;
    }
}

// ---------------- fp32 W[K][N] -> bf16 Wt[N][K] ----------------
__global__ __launch_bounds__(256) void transpose_convert(const float* __restrict__ W,
                                                         u16* __restrict__ Wt, int K, int N) {
    __shared__ float t[32][33];
    int tx = threadIdx.x, ty = threadIdx.y;
    int nt = blockIdx.x * 32, kt = blockIdx.y * 32;
#pragma unroll
    for (int i = 0; i < 4; ++i)
        t[ty + i * 8][tx] = W[(size_t)(kt + ty + i * 8) * N + nt + tx];
    __syncthreads();
#pragma unroll
    for (int i = 0; i < 4; ++i)
        Wt[(size_t)(nt + ty + i * 8) * K + kt + tx] = f2bf(t[tx][ty + i * 8]);
}

// ---------------- vmask + expert row lists (deterministic scan) ----------------
__global__ __launch_bounds__(256) void mask_scan(const int* __restrict__ tt,
                                                 int* __restrict__ lists,
                                                 int* __restrict__ counts) {
    __shared__ int buf[256];
    int tid = threadIdx.x;
    int base = tid * 8;
    int flags = 0, cv = 0;
#pragma unroll
    for (int j = 0; j < 8; ++j) {
        int i = base + j;
        int l = i & (L_SEQ - 1);
        int f = (l < L_SEQ - 1) && (tt[i] == 1) && (tt[i + 1] == 1);
        flags |= f << j; cv += f;
    }
    buf[tid] = cv; __syncthreads();
    for (int d = 1; d < 256; d <<= 1) {
        int t = (tid >= d) ? buf[tid - d] : 0;
        __syncthreads();
        buf[tid] += t;
        __syncthreads();
    }
    int vs = buf[tid] - cv;     // exclusive vis prefix
    int ls = base - vs;         // exclusive lang prefix
    int total_v = buf[255];
#pragma unroll
    for (int j = 0; j < 8; ++j) {
        int i = base + j;
        if ((flags >> j) & 1) lists[vs++] = i;
        else                  lists[2048 + ls++] = i;
    }
    if (tid == 0) { counts[0] = total_v; counts[1] = 2048 - total_v; }
}

// ---------------- 256x256 8-phase bf16 GEMM, indirect A rows, per-expert weights -----
// 512 threads = 8 waves (2M x 4N), per-wave 128x64 output, BK=64, 128 KiB LDS
// (2 tile double-buffer, each tile = 4 x 16KB K-half units: A[k0],B[k0],A[k1],B[k1]).
// Counted vmcnt(4) twice per K-tile (never 0 in main loop); raw s_barrier (no drain).
// LDS chunk XOR-swizzle (chunk ^= (row>>1)&3) via pre-swizzled GLOBAL source
// (gload_lds dest must stay linear) + matching swizzled ds_read addresses.
template <typename OutT>
__global__ __launch_bounds__(512, 2) void gemm_expert(
    const u16* __restrict__ A, const u16* __restrict__ BtVis, const u16* __restrict__ BtLang,
    OutT* __restrict__ C, const int* __restrict__ lists, const int* __restrict__ counts, int ldc) {
    const int e = blockIdx.z;
    const int cnt = counts[e];
    const int m0 = blockIdx.y * 256;
    if (m0 >= cnt) return;
    const u16* Bt = (e == 0) ? BtVis : BtLang;
    const int* list = lists + e * 2048;
    const int n0 = blockIdx.x * 256;
    const int tid = threadIdx.x, lane = tid & 63, w = tid >> 6;
    const int wm = w >> 2, wn = w & 3;          // 2 x 4 wave grid
    const int l16 = lane & 15, quad = lane >> 4;

    // [buf][mat A=0/B=1][khalf][256 rows * 32 elems]  = 128 KiB
    __shared__ __align__(16) u16 lds[2][2][2][8192];

    // ---- staging addresses: thread covers rows r0 (j=0) and 128+r0 (j=1), chunk tid&3
    const int r0 = tid >> 2;                    // 0..127
    const int cs = (tid & 3) ^ ((r0 >> 1) & 3); // swizzled source chunk (same for both j)
    const char* pa0 = (const char*)(A + (size_t)list[min(m0 + r0, cnt - 1)] * D_MODEL) + cs * 16;
    const char* pa1 = (const char*)(A + (size_t)list[min(m0 + 128 + r0, cnt - 1)] * D_MODEL) + cs * 16;
    const char* pb0 = (const char*)(Bt + (size_t)(n0 + r0) * D_MODEL) + cs * 16;
    const char* pb1 = (const char*)(Bt + (size_t)(n0 + 128 + r0) * D_MODEL) + cs * 16;
    const int dst0 = w * 512;                   // u16 index, wave-uniform (lane*16B added by HW)
    const int dst1 = 4096 + w * 512;

    auto STAGE = [&](int buf, int mat, int kh, int tk) {
        const int kbyte = tk * 128 + kh * 64;
        const char* g0 = (mat == 0) ? pa0 : pb0;
        const char* g1 = (mat == 0) ? pa1 : pb1;
        u16* d = &lds[buf][mat][kh][0];
        gload_lds16(g0 + kbyte, d + dst0);
        gload_lds16(g1 + kbyte, d + dst1);
    };

    f32x4 acc[8][4] = {};
    const int NT = D_MODEL / 64;                // 64 K-tiles

    // ---- prologue: stage tile 0 (all 4 units); wait for first two, keep 2 in flight
    STAGE(0, 0, 0, 0); STAGE(0, 1, 0, 0); STAGE(0, 0, 1, 0); STAGE(0, 1, 1, 0);
    WAIT_VM4();
    BAR();

    for (int t = 0; t < NT; ++t) {
        const int c = t & 1, nb = c ^ 1;
        const bool pf = (t + 1 < NT);
        bf16x8 af[4], bf[4];

        // ===== phase 0: (k-sub 0, m-half 0) — 8 ds_read_b128, stage A[k0](t+1)
#pragma unroll
        for (int ni = 0; ni < 4; ++ni) {
            int row = wn * 64 + ni * 16 + l16;
            bf[ni] = *(const bf16x8*)&lds[c][1][0][row * 32 + (quad ^ ((row >> 1) & 3)) * 8];
        }
#pragma unroll
        for (int mi = 0; mi < 4; ++mi) {
            int row = wm * 128 + mi * 16 + l16;
            af[mi] = *(const bf16x8*)&lds[c][0][0][row * 32 + (quad ^ ((row >> 1) & 3)) * 8];
        }
        if (pf) STAGE(nb, 0, 0, t + 1);
        BAR();
        __builtin_amdgcn_s_setprio(1);
#pragma unroll
        for (int mi = 0; mi < 4; ++mi)
#pragma unroll
            for (int ni = 0; ni < 4; ++ni)
                acc[mi][ni] = mfma_bf16(af[mi], bf[ni], acc[mi][ni]);
        __builtin_amdgcn_s_setprio(0);
        BAR();

        // ===== phase 1: (k-sub 0, m-half 1) — 4 ds_read_b128, stage B[k0](t+1)
#pragma unroll
        for (int mi = 0; mi < 4; ++mi) {
            int row = wm * 128 + 64 + mi * 16 + l16;
            af[mi] = *(const bf16x8*)&lds[c][0][0][row * 32 + (quad ^ ((row >> 1) & 3)) * 8];
        }
        if (pf) STAGE(nb, 1, 0, t + 1);
        BAR();
        __builtin_amdgcn_s_setprio(1);
#pragma unroll
        for (int mi = 0; mi < 4; ++mi)
#pragma unroll
            for (int ni = 0; ni < 4; ++ni)
                acc[4 + mi][ni] = mfma_bf16(af[mi], bf[ni], acc[4 + mi][ni]);
        __builtin_amdgcn_s_setprio(0);
        // guard phase-2 reads: A[k1](t), B[k1](t) must be landed everywhere
        if (pf) WAIT_VM4(); else WAIT_VM0();
        BAR();

        // ===== phase 2: (k-sub 1, m-half 0) — 8 ds_read_b128, stage A[k1](t+1)
#pragma unroll
        for (int ni = 0; ni < 4; ++ni) {
            int row = wn * 64 + ni * 16 + l16;
            bf[ni] = *(const bf16x8*)&lds[c][1][1][row * 32 + (quad ^ ((row >> 1) & 3)) * 8];
        }
#pragma unroll
        for (int mi = 0; mi < 4; ++mi) {
            int row = wm * 128 + mi * 16 + l16;
            af[mi] = *(const bf16x8*)&lds[c][0][1][row * 32 + (quad ^ ((row >> 1) & 3)) * 8];
        }
        if (pf) STAGE(nb, 0, 1, t + 1);
        BAR();
        __builtin_amdgcn_s_setprio(1);
#pragma unroll
        for (int mi = 0; mi < 4; ++mi)
#pragma unroll
            for (int ni = 0; ni < 4; ++ni)
                acc[mi][ni] = mfma_bf16(af[mi], bf[ni], acc[mi][ni]);
        __builtin_amdgcn_s_setprio(0);
        BAR();

        // ===== phase 3: (k-sub 1, m-half 1) — 4 ds_read_b128, stage B[k1](t+1)
#pragma unroll
        for (int mi = 0; mi < 4; ++mi) {
            int row = wm * 128 + 64 + mi * 16 + l16;
            af[mi] = *(const bf16x8*)&lds[c][0][1][row * 32 + (quad ^ ((row >> 1) & 3)) * 8];
        }
        if (pf) STAGE(nb, 1, 1, t + 1);
        BAR();
        __builtin_amdgcn_s_setprio(1);
#pragma unroll
        for (int mi = 0; mi < 4; ++mi)
#pragma unroll
            for (int ni = 0; ni < 4; ++ni)
                acc[4 + mi][ni] = mfma_bf16(af[mi], bf[ni], acc[4 + mi][ni]);
        __builtin_amdgcn_s_setprio(0);
        // guard next tile's phase-0 reads: A[k0](t+1), B[k0](t+1)
        if (pf) WAIT_VM4();
        BAR();
    }

    // ---- epilogue: per-wave 128x64 at (wm*128, wn*64)
#pragma unroll
    for (int mf = 0; mf < 8; ++mf) {
#pragma unroll
        for (int r = 0; r < 4; ++r) {
            int slot = m0 + wm * 128 + mf * 16 + quad * 4 + r;
            if (slot < cnt) {
                int row = list[slot];
                size_t rb = (size_t)row * ldc + n0 + wn * 64 + l16;
#pragma unroll
                for (int ni = 0; ni < 4; ++ni) {
                    float v = acc[mf][ni][r];
                    if constexpr (sizeof(OutT) == 2) C[rb + ni * 16] = (OutT)f2bf(v);
                    else                             C[rb + ni * 16] = v;
                }
            }
        }
    }
}

// ---------------- RoPE in-place on q,k halves of QKV (bf16) ----------------
__global__ __launch_bounds__(256) void rope_kernel(u16* __restrict__ qkv,
                                                   const int* __restrict__ posi) {
    int idx = blockIdx.x * 256 + threadIdx.x;    // [0, 2048*32*64)
    int t = idx >> 11;
    int rem = idx & 2047;
    int h = rem >> 6;
    int j = rem & 63;
    int l = t & (L_SEQ - 1);
    int is_i32 = posi[1];                          // 1 => int32 layout, 0 => int64 layout
    int pv = is_i32 ? posi[l] : posi[2 * l];       // int64 low word (positions < 2^31)
    float p = (float)pv;
    float inv = expf(-(float)j * 0.14391156831212787f);  // ln(10000)/64
    float ang = p * inv;
    float s, c;
    sincosf(ang, &s, &c);
    size_t base = (size_t)t * NQKV + h * DH + j;
    float x1 = bf2f(qkv[base]), x2 = bf2f(qkv[base + 64]);
    qkv[base]      = f2bf(x1 * c - x2 * s);
    qkv[base + 64] = f2bf(x2 * c + x1 * s);
    size_t kb = base + D_MODEL;
    x1 = bf2f(qkv[kb]); x2 = bf2f(qkv[kb + 64]);
    qkv[kb]      = f2bf(x1 * c - x2 * s);
    qkv[kb + 64] = f2bf(x2 * c + x1 * s);
}

// ---------------- flash attention (causal), MFMA QK^T and PV ----------------
__global__ __launch_bounds__(256) void attn_kernel(const u16* __restrict__ qkv,
                                                   u16* __restrict__ ctx) {
    const int qt = blockIdx.x, h = blockIdx.y, b = blockIdx.z;
    const int tid = threadIdx.x, lane = tid & 63, w = tid >> 6;
    const int quad = lane >> 4, l16 = lane & 15;

    __shared__ __align__(16) u16 Qs[64 * 128];
    __shared__ __align__(16) u16 Ks[32 * 128];
    __shared__ __align__(16) u16 Vt[128 * 32];
    __shared__ __align__(16) u16 Ps[4][16 * 32];

    const size_t qbase = ((size_t)(b * L_SEQ + qt * 64)) * NQKV + h * DH;
    for (int idx = tid; idx < 64 * 16; idx += 256) {
        int r = idx >> 4, c = idx & 15;
        *(u16x8*)&Qs[r * 128 + c * 8] = *(const u16x8*)&qkv[qbase + (size_t)r * NQKV + c * 8];
    }

    float m_i[4], l_i[4];
    f32x4 o[8] = {};
#pragma unroll
    for (int r = 0; r < 4; ++r) { m_i[r] = -1e30f; l_i[r] = 0.f; }
    const float scale = 0.08838834764831845f;  // 1/sqrt(128)
    const int jmax = 2 * qt + 2;

    for (int jt = 0; jt < jmax; ++jt) {
        __syncthreads();
        const size_t kb = ((size_t)(b * L_SEQ + jt * 32)) * NQKV + D_MODEL + h * DH;
        const size_t vb = kb + D_MODEL;
        for (int idx = tid; idx < 32 * 16; idx += 256) {
            int r = idx >> 4, c = idx & 15;
            *(u16x8*)&Ks[r * 128 + c * 8] = *(const u16x8*)&qkv[kb + (size_t)r * NQKV + c * 8];
            u16x8 v = *(const u16x8*)&qkv[vb + (size_t)r * NQKV + c * 8];
#pragma unroll
            for (int jj = 0; jj < 8; ++jj) Vt[(c * 8 + jj) * 32 + r] = v[jj];
        }
        __syncthreads();

        f32x4 s0 = {0.f, 0.f, 0.f, 0.f}, s1 = {0.f, 0.f, 0.f, 0.f};
#pragma unroll
        for (int kc = 0; kc < 4; ++kc) {
            bf16x8 aq  = *(const bf16x8*)&Qs[(w * 16 + l16) * 128 + kc * 32 + quad * 8];
            bf16x8 bk0 = *(const bf16x8*)&Ks[l16 * 128 + kc * 32 + quad * 8];
            bf16x8 bk1 = *(const bf16x8*)&Ks[(16 + l16) * 128 + kc * 32 + quad * 8];
            s0 = mfma_bf16(aq, bk0, s0);
            s1 = mfma_bf16(aq, bk1, s1);
        }

        const int qg = qt * 64 + w * 16 + quad * 4;
        const int kg0 = jt * 32 + l16, kg1 = kg0 + 16;
        float sv0[4], sv1[4], mx[4];
#pragma unroll
        for (int r = 0; r < 4; ++r) {
            sv0[r] = (kg0 <= qg + r) ? s0[r] * scale : -1e30f;
            sv1[r] = (kg1 <= qg + r) ? s1[r] * scale : -1e30f;
            mx[r] = fmaxf(sv0[r], sv1[r]);
        }
#pragma unroll
        for (int d = 1; d < 16; d <<= 1)
#pragma unroll
            for (int r = 0; r < 4; ++r) mx[r] = fmaxf(mx[r], __shfl_xor(mx[r], d));
        float alpha[4], p0[4], p1[4], rs[4];
#pragma unroll
        for (int r = 0; r < 4; ++r) {
            float mn = fmaxf(m_i[r], mx[r]);
            alpha[r] = __expf(m_i[r] - mn);
            m_i[r] = mn;
            p0[r] = __expf(sv0[r] - mn);
            p1[r] = __expf(sv1[r] - mn);
            rs[r] = p0[r] + p1[r];
        }
#pragma unroll
        for (int d = 1; d < 16; d <<= 1)
#pragma unroll
            for (int r = 0; r < 4; ++r) rs[r] += __shfl_xor(rs[r], d);
#pragma unroll
        for (int r = 0; r < 4; ++r) {
            l_i[r] = l_i[r] * alpha[r] + rs[r];
            Ps[w][(quad * 4 + r) * 32 + l16]      = f2bf(p0[r]);
            Ps[w][(quad * 4 + r) * 32 + 16 + l16] = f2bf(p1[r]);
        }
#pragma unroll
        for (int n = 0; n < 8; ++n)
#pragma unroll
            for (int r = 0; r < 4; ++r) o[n][r] *= alpha[r];
        __syncthreads();  // P C-layout -> A-layout LDS round-trip visibility
        bf16x8 ap = *(const bf16x8*)&Ps[w][l16 * 32 + quad * 8];
#pragma unroll
        for (int n = 0; n < 8; ++n) {
            bf16x8 bv = *(const bf16x8*)&Vt[(n * 16 + l16) * 32 + quad * 8];
            o[n] = mfma_bf16(ap, bv, o[n]);
        }
    }

    const int tglob = b * L_SEQ + qt * 64 + w * 16 + quad * 4;
#pragma unroll
    for (int r = 0; r < 4; ++r) {
        float invl = 1.f / l_i[r];
#pragma unroll
        for (int n = 0; n < 8; ++n)
            ctx[(size_t)(tglob + r) * D_MODEL + h * DH + n * 16 + l16] = f2bf(o[n][r] * invl);
    }
}

extern "C" void kernel_launch(void* const* d_in, const int* in_sizes, int n_in,
                              void* d_out, int out_size, void* d_ws, size_t ws_size,
                              hipStream_t stream) {
    const float* hidden = (const float*)d_in[0];
    const int* tt = (const int*)d_in[1];
    const int* pos = (const int*)d_in[2];
    const float* wqv = (const float*)d_in[3];
    const float* wql = (const float*)d_in[4];
    const float* wdv = (const float*)d_in[5];
    const float* wdl = (const float*)d_in[6];
    float* out = (float*)d_out;

    char* ws = (char*)d_ws;
    size_t off = 0;
    auto alloc = [&](size_t bytes) {
        char* p = ws + off;
        off += (bytes + 255) & ~(size_t)255;
        return p;
    };
    u16* WqvT = (u16*)alloc((size_t)NQKV * D_MODEL * 2);
    u16* WqlT = (u16*)alloc((size_t)NQKV * D_MODEL * 2);
    u16* WdvT = (u16*)alloc((size_t)D_MODEL * D_MODEL * 2);
    u16* WdlT = (u16*)alloc((size_t)D_MODEL * D_MODEL * 2);
    u16* Abf  = (u16*)alloc((size_t)BL * D_MODEL * 2);
    u16* QKV  = (u16*)alloc((size_t)BL * NQKV * 2);
    u16* CTX  = (u16*)alloc((size_t)BL * D_MODEL * 2);
    int* lists  = (int*)alloc(4096 * sizeof(int));
    int* counts = (int*)alloc(256);

    convert_f32_bf16<<<BL * D_MODEL / 4 / 256, 256, 0, stream>>>(hidden, Abf, BL * D_MODEL / 4);
    transpose_convert<<<dim3(NQKV / 32, D_MODEL / 32), dim3(32, 8), 0, stream>>>(wqv, WqvT, D_MODEL, NQKV);
    transpose_convert<<<dim3(NQKV / 32, D_MODEL / 32), dim3(32, 8), 0, stream>>>(wql, WqlT, D_MODEL, NQKV);
    transpose_convert<<<dim3(D_MODEL / 32, D_MODEL / 32), dim3(32, 8), 0, stream>>>(wdv, WdvT, D_MODEL, D_MODEL);
    transpose_convert<<<dim3(D_MODEL / 32, D_MODEL / 32), dim3(32, 8), 0, stream>>>(wdl, WdlT, D_MODEL, D_MODEL);
    mask_scan<<<1, 256, 0, stream>>>(tt, lists, counts);
    gemm_expert<u16><<<dim3(NQKV / 256, 8, 2), 512, 0, stream>>>(Abf, WqvT, WqlT, QKV, lists, counts, NQKV);
    rope_kernel<<<BL * NH * 64 / 256, 256, 0, stream>>>(QKV, pos);
    attn_kernel<<<dim3(16, NH, 2), 256, 0, stream>>>(QKV, CTX);
    gemm_expert<float><<<dim3(D_MODEL / 256, 8, 2), 512, 0, stream>>>(CTX, WdvT, WdlT, out, lists, counts, D_MODEL);
}

// Round 2
// 1025.301 us; speedup vs baseline: 1.3468x; 1.1753x over previous
//
#include <hip/hip_runtime.h>
#include <math.h>

typedef unsigned short u16;
typedef __attribute__((ext_vector_type(4))) float f32x4;
typedef __attribute__((ext_vector_type(8))) __bf16 bf16x8;
typedef __attribute__((ext_vector_type(8))) u16 u16x8;
typedef __attribute__((ext_vector_type(4))) u16 u16x4;

#define D_MODEL 4096
#define NQKV    12288
#define BL      2048
#define L_SEQ   1024
#define NH      32
#define DH      128

__device__ __forceinline__ u16 f2bf(float f) {
    union { float f; unsigned u; } v; v.f = f;
    unsigned r = (v.u + 0x7fffu + ((v.u >> 16) & 1u)) >> 16;
    return (u16)r;
}
__device__ __forceinline__ float bf2f(u16 b) {
    union { unsigned u; float f; } v; v.u = ((unsigned)b) << 16;
    return v.f;
}
__device__ __forceinline__ void gload_lds16(const void* g, void* l) {
    __builtin_amdgcn_global_load_lds((const __attribute__((address_space(1))) void*)g,
                                     (__attribute__((address_space(3))) void*)l, 16, 0, 0);
}
__device__ __forceinline__ f32x4 mfma_bf16(bf16x8 a, bf16x8 b, f32x4 c) {
    return __builtin_amdgcn_mfma_f32_16x16x32_bf16(a, b, c, 0, 0, 0);
}

// raw barrier (no implicit vmcnt(0) drain) + compiler memory fence
#define BAR()      asm volatile("s_barrier" ::: "memory")
#define WAIT_VM4() asm volatile("s_waitcnt vmcnt(4)" ::: "memory")
#define WAIT_VM0() asm volatile("s_waitcnt vmcnt(0)" ::: "memory")

// ---------------- fp32 -> bf16 convert (hidden states) ----------------
__global__ __launch_bounds__(256) void convert_f32_bf16(const float* __restrict__ in,
                                                        u16* __restrict__ out, int n4) {
    int i = blockIdx.x * 256 + threadIdx.x;
    if (i < n4) {
        float4 v = ((const float4*)in)[i];
        u16x4 o;
        o[0] = f2bf(v.x); o[1] = f2bf(v.y); o[2] = f2bf(v.z); o[3] = f2bf(v.w);
        ((u16x4*)out)[i] = o;
    }
}

// ---------------- fp32 W[K][N] -> bf16 Wt[N][K] ----------------
__global__ __launch_bounds__(256) void transpose_convert(const float* __restrict__ W,
                                                         u16* __restrict__ Wt, int K, int N) {
    __shared__ float t[32][33];
    int tx = threadIdx.x, ty = threadIdx.y;
    int nt = blockIdx.x * 32, kt = blockIdx.y * 32;
#pragma unroll
    for (int i = 0; i < 4; ++i)
        t[ty + i * 8][tx] = W[(size_t)(kt + ty + i * 8) * N + nt + tx];
    __syncthreads();
#pragma unroll
    for (int i = 0; i < 4; ++i)
        Wt[(size_t)(nt + ty + i * 8) * K + kt + tx] = f2bf(t[tx][ty + i * 8]);
}

// ---------------- vmask + expert row lists (deterministic scan) ----------------
__global__ __launch_bounds__(256) void mask_scan(const int* __restrict__ tt,
                                                 int* __restrict__ lists,
                                                 int* __restrict__ counts) {
    __shared__ int buf[256];
    int tid = threadIdx.x;
    int base = tid * 8;
    int flags = 0, cv = 0;
#pragma unroll
    for (int j = 0; j < 8; ++j) {
        int i = base + j;
        int l = i & (L_SEQ - 1);
        int f = (l < L_SEQ - 1) && (tt[i] == 1) && (tt[i + 1] == 1);
        flags |= f << j; cv += f;
    }
    buf[tid] = cv; __syncthreads();
    for (int d = 1; d < 256; d <<= 1) {
        int t = (tid >= d) ? buf[tid - d] : 0;
        __syncthreads();
        buf[tid] += t;
        __syncthreads();
    }
    int vs = buf[tid] - cv;     // exclusive vis prefix
    int ls = base - vs;         // exclusive lang prefix
    int total_v = buf[255];
#pragma unroll
    for (int j = 0; j < 8; ++j) {
        int i = base + j;
        if ((flags >> j) & 1) lists[vs++] = i;
        else                  lists[2048 + ls++] = i;
    }
    if (tid == 0) { counts[0] = total_v; counts[1] = 2048 - total_v; }
}

// ---------------- 256x256 8-phase bf16 GEMM, indirect A rows, per-expert weights -----
template <typename OutT>
__global__ __launch_bounds__(512, 2) void gemm_expert(
    const u16* __restrict__ A, const u16* __restrict__ BtVis, const u16* __restrict__ BtLang,
    OutT* __restrict__ C, const int* __restrict__ lists, const int* __restrict__ counts, int ldc) {
    const int e = blockIdx.z;
    const int cnt = counts[e];
    const int m0 = blockIdx.y * 256;
    if (m0 >= cnt) return;
    const u16* Bt = (e == 0) ? BtVis : BtLang;
    const int* list = lists + e * 2048;
    const int n0 = blockIdx.x * 256;
    const int tid = threadIdx.x, lane = tid & 63, w = tid >> 6;
    const int wm = w >> 2, wn = w & 3;          // 2 x 4 wave grid
    const int l16 = lane & 15, quad = lane >> 4;

    // [buf][mat A=0/B=1][khalf][256 rows * 32 elems]  = 128 KiB
    __shared__ __align__(16) u16 lds[2][2][2][8192];

    const int r0 = tid >> 2;                    // 0..127
    const int cs = (tid & 3) ^ ((r0 >> 1) & 3); // swizzled source chunk (same for both j)
    const char* pa0 = (const char*)(A + (size_t)list[min(m0 + r0, cnt - 1)] * D_MODEL) + cs * 16;
    const char* pa1 = (const char*)(A + (size_t)list[min(m0 + 128 + r0, cnt - 1)] * D_MODEL) + cs * 16;
    const char* pb0 = (const char*)(Bt + (size_t)(n0 + r0) * D_MODEL) + cs * 16;
    const char* pb1 = (const char*)(Bt + (size_t)(n0 + 128 + r0) * D_MODEL) + cs * 16;
    const int dst0 = w * 512;                   // u16 index, wave-uniform (lane*16B added by HW)
    const int dst1 = 4096 + w * 512;

    auto STAGE = [&](int buf, int mat, int kh, int tk) {
        const int kbyte = tk * 128 + kh * 64;
        const char* g0 = (mat == 0) ? pa0 : pb0;
        const char* g1 = (mat == 0) ? pa1 : pb1;
        u16* d = &lds[buf][mat][kh][0];
        gload_lds16(g0 + kbyte, d + dst0);
        gload_lds16(g1 + kbyte, d + dst1);
    };

    f32x4 acc[8][4] = {};
    const int NT = D_MODEL / 64;                // 64 K-tiles

    STAGE(0, 0, 0, 0); STAGE(0, 1, 0, 0); STAGE(0, 0, 1, 0); STAGE(0, 1, 1, 0);
    WAIT_VM4();
    BAR();

    for (int t = 0; t < NT; ++t) {
        const int c = t & 1, nb = c ^ 1;
        const bool pf = (t + 1 < NT);
        bf16x8 af[4], bf[4];

        // ===== phase 0: (k-sub 0, m-half 0)
#pragma unroll
        for (int ni = 0; ni < 4; ++ni) {
            int row = wn * 64 + ni * 16 + l16;
            bf[ni] = *(const bf16x8*)&lds[c][1][0][row * 32 + (quad ^ ((row >> 1) & 3)) * 8];
        }
#pragma unroll
        for (int mi = 0; mi < 4; ++mi) {
            int row = wm * 128 + mi * 16 + l16;
            af[mi] = *(const bf16x8*)&lds[c][0][0][row * 32 + (quad ^ ((row >> 1) & 3)) * 8];
        }
        if (pf) STAGE(nb, 0, 0, t + 1);
        BAR();
        __builtin_amdgcn_s_setprio(1);
#pragma unroll
        for (int mi = 0; mi < 4; ++mi)
#pragma unroll
            for (int ni = 0; ni < 4; ++ni)
                acc[mi][ni] = mfma_bf16(af[mi], bf[ni], acc[mi][ni]);
        __builtin_amdgcn_s_setprio(0);
        BAR();

        // ===== phase 1: (k-sub 0, m-half 1)
#pragma unroll
        for (int mi = 0; mi < 4; ++mi) {
            int row = wm * 128 + 64 + mi * 16 + l16;
            af[mi] = *(const bf16x8*)&lds[c][0][0][row * 32 + (quad ^ ((row >> 1) & 3)) * 8];
        }
        if (pf) STAGE(nb, 1, 0, t + 1);
        BAR();
        __builtin_amdgcn_s_setprio(1);
#pragma unroll
        for (int mi = 0; mi < 4; ++mi)
#pragma unroll
            for (int ni = 0; ni < 4; ++ni)
                acc[4 + mi][ni] = mfma_bf16(af[mi], bf[ni], acc[4 + mi][ni]);
        __builtin_amdgcn_s_setprio(0);
        if (pf) WAIT_VM4(); else WAIT_VM0();
        BAR();

        // ===== phase 2: (k-sub 1, m-half 0)
#pragma unroll
        for (int ni = 0; ni < 4; ++ni) {
            int row = wn * 64 + ni * 16 + l16;
            bf[ni] = *(const bf16x8*)&lds[c][1][1][row * 32 + (quad ^ ((row >> 1) & 3)) * 8];
        }
#pragma unroll
        for (int mi = 0; mi < 4; ++mi) {
            int row = wm * 128 + mi * 16 + l16;
            af[mi] = *(const bf16x8*)&lds[c][0][1][row * 32 + (quad ^ ((row >> 1) & 3)) * 8];
        }
        if (pf) STAGE(nb, 0, 1, t + 1);
        BAR();
        __builtin_amdgcn_s_setprio(1);
#pragma unroll
        for (int mi = 0; mi < 4; ++mi)
#pragma unroll
            for (int ni = 0; ni < 4; ++ni)
                acc[mi][ni] = mfma_bf16(af[mi], bf[ni], acc[mi][ni]);
        __builtin_amdgcn_s_setprio(0);
        BAR();

        // ===== phase 3: (k-sub 1, m-half 1)
#pragma unroll
        for (int mi = 0; mi < 4; ++mi) {
            int row = wm * 128 + 64 + mi * 16 + l16;
            af[mi] = *(const bf16x8*)&lds[c][0][1][row * 32 + (quad ^ ((row >> 1) & 3)) * 8];
        }
        if (pf) STAGE(nb, 1, 1, t + 1);
        BAR();
        __builtin_amdgcn_s_setprio(1);
#pragma unroll
        for (int mi = 0; mi < 4; ++mi)
#pragma unroll
            for (int ni = 0; ni < 4; ++ni)
                acc[4 + mi][ni] = mfma_bf16(af[mi], bf[ni], acc[4 + mi][ni]);
        __builtin_amdgcn_s_setprio(0);
        if (pf) WAIT_VM4();
        BAR();
    }

    // ---- epilogue: per-wave 128x64 at (wm*128, wn*64)
#pragma unroll
    for (int mf = 0; mf < 8; ++mf) {
#pragma unroll
        for (int r = 0; r < 4; ++r) {
            int slot = m0 + wm * 128 + mf * 16 + quad * 4 + r;
            if (slot < cnt) {
                int row = list[slot];
                size_t rb = (size_t)row * ldc + n0 + wn * 64 + l16;
#pragma unroll
                for (int ni = 0; ni < 4; ++ni) {
                    float v = acc[mf][ni][r];
                    if constexpr (sizeof(OutT) == 2) C[rb + ni * 16] = (OutT)f2bf(v);
                    else                             C[rb + ni * 16] = v;
                }
            }
        }
    }
}

// ---------------- RoPE in-place on q,k halves of QKV (bf16) ----------------
__global__ __launch_bounds__(256) void rope_kernel(u16* __restrict__ qkv,
                                                   const int* __restrict__ posi) {
    int idx = blockIdx.x * 256 + threadIdx.x;    // [0, 2048*32*64)
    int t = idx >> 11;
    int rem = idx & 2047;
    int h = rem >> 6;
    int j = rem & 63;
    int l = t & (L_SEQ - 1);
    int is_i32 = posi[1];                          // 1 => int32 layout, 0 => int64 layout
    int pv = is_i32 ? posi[l] : posi[2 * l];       // int64 low word (positions < 2^31)
    float p = (float)pv;
    float inv = expf(-(float)j * 0.14391156831212787f);  // ln(10000)/64
    float ang = p * inv;
    float s, c;
    sincosf(ang, &s, &c);
    size_t base = (size_t)t * NQKV + h * DH + j;
    float x1 = bf2f(qkv[base]), x2 = bf2f(qkv[base + 64]);
    qkv[base]      = f2bf(x1 * c - x2 * s);
    qkv[base + 64] = f2bf(x2 * c + x1 * s);
    size_t kb = base + D_MODEL;
    x1 = bf2f(qkv[kb]); x2 = bf2f(qkv[kb + 64]);
    qkv[kb]      = f2bf(x1 * c - x2 * s);
    qkv[kb + 64] = f2bf(x2 * c + x1 * s);
}

// ---------------- flash attention (causal), KVBLK=64, pipelined, swizzled LDS ------
// 4 waves x 16 q-rows = 64 q-rows per block. Q in registers (read once).
// Per jt: prefetch K/V(jt+1) to regs -> QK^T (16 mfma) -> in-reg softmax ->
// Ps (per-warp LDS, no barrier needed) -> PV (16 mfma) -> write K/V(jt+1) to
// LDS buf^1 -> single __syncthreads.
// Swizzles: Ks chunk ^= row&7 (both sides reg-staged). Vt (transposed V [d][key])
// chunk ^= (d ^ (d>>3)) & 7  -- spreads BOTH the scalar transpose writes (vary in
// d>>3) AND the b128 fragment reads (vary in d&7). Ps chunk ^= q&7.
__global__ __launch_bounds__(256, 2) void attn_kernel(const u16* __restrict__ qkv,
                                                      u16* __restrict__ ctx) {
    const int qt = (int)gridDim.x - 1 - (int)blockIdx.x;   // longest blocks first
    const int h = blockIdx.y, b = blockIdx.z;
    const int tid = threadIdx.x, lane = tid & 63, w = tid >> 6;
    const int quad = lane >> 4, l16 = lane & 15;

    __shared__ __align__(16) u16 Ks[2][64 * 128];
    __shared__ __align__(16) u16 Vt[2][128 * 64];
    __shared__ __align__(16) u16 Ps[4][16 * 64];

    // --- Q fragments directly into registers (A-frag row = l16 -> q = w*16+l16) ---
    const size_t qbase = ((size_t)(b * L_SEQ + qt * 64 + w * 16 + l16)) * NQKV + h * DH;
    bf16x8 aq[4];
#pragma unroll
    for (int kc = 0; kc < 4; ++kc)
        aq[kc] = *(const bf16x8*)&qkv[qbase + kc * 32 + quad * 8];

    // staging coords: thread covers 4 (row, chunk) pairs of the 64x128 K/V tile
    int srow[4], schk[4];
#pragma unroll
    for (int i = 0; i < 4; ++i) {
        int idx = i * 256 + tid;
        srow[i] = idx >> 4;
        schk[i] = idx & 15;
    }
    const size_t kv0 = ((size_t)(b * L_SEQ)) * NQKV + D_MODEL + h * DH;

    float m_i[4], l_i[4];
    f32x4 o[8] = {};
#pragma unroll
    for (int r = 0; r < 4; ++r) { m_i[r] = -1e30f; l_i[r] = 0.f; }
    const float scale = 0.08838834764831845f;  // 1/sqrt(128)
    const int jmax = qt + 1;

    // ---- prologue: stage tile 0 into buf 0 ----
    {
        u16x8 kr[4], vr[4];
#pragma unroll
        for (int i = 0; i < 4; ++i) {
            size_t g = kv0 + (size_t)srow[i] * NQKV + schk[i] * 8;
            kr[i] = *(const u16x8*)&qkv[g];
            vr[i] = *(const u16x8*)&qkv[g + D_MODEL];
        }
#pragma unroll
        for (int i = 0; i < 4; ++i) {
            int r = srow[i], c = schk[i];
            *(u16x8*)&Ks[0][r * 128 + ((c ^ (r & 7)) * 8)] = kr[i];
#pragma unroll
            for (int e = 0; e < 8; ++e) {
                int d = c * 8 + e;
                int sw = (r >> 3) ^ ((d ^ (d >> 3)) & 7);
                Vt[0][d * 64 + sw * 8 + (r & 7)] = vr[i][e];
            }
        }
    }
    __syncthreads();

    for (int jt = 0; jt < jmax; ++jt) {
        const int cur = jt & 1;
        const bool pf = (jt + 1 < jmax);

        // ---- issue next tile's global loads (latency hides under compute) ----
        u16x8 kr[4], vr[4];
        if (pf) {
            const size_t kb = kv0 + (size_t)((jt + 1) * 64) * NQKV;
#pragma unroll
            for (int i = 0; i < 4; ++i) {
                size_t g = kb + (size_t)srow[i] * NQKV + schk[i] * 8;
                kr[i] = *(const u16x8*)&qkv[g];
                vr[i] = *(const u16x8*)&qkv[g + D_MODEL];
            }
        }

        // ---- QK^T: 4 key-subtiles x 4 k-chunks ----
        f32x4 s[4] = {};
        __builtin_amdgcn_s_setprio(1);
#pragma unroll
        for (int sub = 0; sub < 4; ++sub) {
            const int row = sub * 16 + l16;
#pragma unroll
            for (int kc = 0; kc < 4; ++kc) {
                bf16x8 bk = *(const bf16x8*)&Ks[cur][row * 128 + (((kc * 4 + quad) ^ (row & 7)) * 8)];
                s[sub] = mfma_bf16(aq[kc], bk, s[sub]);
            }
        }
        __builtin_amdgcn_s_setprio(0);

        // ---- masked online softmax (rows = q = quad*4+r, cols = key = sub*16+l16) ----
        const int qg = qt * 64 + w * 16 + quad * 4;
        float p[4][4], mx[4];
#pragma unroll
        for (int r = 0; r < 4; ++r) mx[r] = -1e30f;
#pragma unroll
        for (int sub = 0; sub < 4; ++sub) {
            const int kg = jt * 64 + sub * 16 + l16;
#pragma unroll
            for (int r = 0; r < 4; ++r) {
                float sv = (kg <= qg + r) ? s[sub][r] * scale : -1e30f;
                p[sub][r] = sv;
                mx[r] = fmaxf(mx[r], sv);
            }
        }
#pragma unroll
        for (int d = 1; d < 16; d <<= 1)
#pragma unroll
            for (int r = 0; r < 4; ++r) mx[r] = fmaxf(mx[r], __shfl_xor(mx[r], d));
        float alpha[4], rs[4];
#pragma unroll
        for (int r = 0; r < 4; ++r) {
            float mn = fmaxf(m_i[r], mx[r]);
            alpha[r] = __expf(m_i[r] - mn);
            m_i[r] = mn;
            rs[r] = 0.f;
        }
#pragma unroll
        for (int sub = 0; sub < 4; ++sub)
#pragma unroll
            for (int r = 0; r < 4; ++r) {
                p[sub][r] = __expf(p[sub][r] - m_i[r]);
                rs[r] += p[sub][r];
            }
#pragma unroll
        for (int d = 1; d < 16; d <<= 1)
#pragma unroll
            for (int r = 0; r < 4; ++r) rs[r] += __shfl_xor(rs[r], d);

        // ---- P -> per-warp LDS (C-layout -> A-layout); no barrier needed ----
#pragma unroll
        for (int sub = 0; sub < 4; ++sub)
#pragma unroll
            for (int r = 0; r < 4; ++r) {
                const int q = quad * 4 + r;
                const int chunk = sub * 2 + (l16 >> 3);
                Ps[w][q * 64 + ((chunk ^ (q & 7)) * 8) + (l16 & 7)] = f2bf(p[sub][r]);
            }
#pragma unroll
        for (int r = 0; r < 4; ++r) l_i[r] = l_i[r] * alpha[r] + rs[r];
#pragma unroll
        for (int n = 0; n < 8; ++n)
#pragma unroll
            for (int r = 0; r < 4; ++r) o[n][r] *= alpha[r];

        // ---- PV: 2 k-halves x 8 d-chunks ----
        __builtin_amdgcn_s_setprio(1);
#pragma unroll
        for (int ks = 0; ks < 2; ++ks) {
            bf16x8 ap = *(const bf16x8*)&Ps[w][l16 * 64 + (((ks * 4 + quad) ^ (l16 & 7)) * 8)];
#pragma unroll
            for (int n = 0; n < 8; ++n) {
                const int d = n * 16 + l16;
                bf16x8 bv = *(const bf16x8*)&Vt[cur][d * 64 + (((ks * 4 + quad) ^ ((d ^ (d >> 3)) & 7)) * 8)];
                o[n] = mfma_bf16(ap, bv, o[n]);
            }
        }
        __builtin_amdgcn_s_setprio(0);

        // ---- write prefetched tile into the other buffer, single barrier ----
        if (pf) {
            const int nb = cur ^ 1;
#pragma unroll
            for (int i = 0; i < 4; ++i) {
                int r = srow[i], c = schk[i];
                *(u16x8*)&Ks[nb][r * 128 + ((c ^ (r & 7)) * 8)] = kr[i];
#pragma unroll
                for (int e = 0; e < 8; ++e) {
                    int d = c * 8 + e;
                    int sw = (r >> 3) ^ ((d ^ (d >> 3)) & 7);
                    Vt[nb][d * 64 + sw * 8 + (r & 7)] = vr[i][e];
                }
            }
        }
        __syncthreads();
    }

    const int tglob = b * L_SEQ + qt * 64 + w * 16 + quad * 4;
#pragma unroll
    for (int r = 0; r < 4; ++r) {
        float invl = 1.f / l_i[r];
#pragma unroll
        for (int n = 0; n < 8; ++n)
            ctx[(size_t)(tglob + r) * D_MODEL + h * DH + n * 16 + l16] = f2bf(o[n][r] * invl);
    }
}

extern "C" void kernel_launch(void* const* d_in, const int* in_sizes, int n_in,
                              void* d_out, int out_size, void* d_ws, size_t ws_size,
                              hipStream_t stream) {
    const float* hidden = (const float*)d_in[0];
    const int* tt = (const int*)d_in[1];
    const int* pos = (const int*)d_in[2];
    const float* wqv = (const float*)d_in[3];
    const float* wql = (const float*)d_in[4];
    const float* wdv = (const float*)d_in[5];
    const float* wdl = (const float*)d_in[6];
    float* out = (float*)d_out;

    char* ws = (char*)d_ws;
    size_t off = 0;
    auto alloc = [&](size_t bytes) {
        char* p = ws + off;
        off += (bytes + 255) & ~(size_t)255;
        return p;
    };
    u16* WqvT = (u16*)alloc((size_t)NQKV * D_MODEL * 2);
    u16* WqlT = (u16*)alloc((size_t)NQKV * D_MODEL * 2);
    u16* WdvT = (u16*)alloc((size_t)D_MODEL * D_MODEL * 2);
    u16* WdlT = (u16*)alloc((size_t)D_MODEL * D_MODEL * 2);
    u16* Abf  = (u16*)alloc((size_t)BL * D_MODEL * 2);
    u16* QKV  = (u16*)alloc((size_t)BL * NQKV * 2);
    u16* CTX  = (u16*)alloc((size_t)BL * D_MODEL * 2);
    int* lists  = (int*)alloc(4096 * sizeof(int));
    int* counts = (int*)alloc(256);

    convert_f32_bf16<<<BL * D_MODEL / 4 / 256, 256, 0, stream>>>(hidden, Abf, BL * D_MODEL / 4);
    transpose_convert<<<dim3(NQKV / 32, D_MODEL / 32), dim3(32, 8), 0, stream>>>(wqv, WqvT, D_MODEL, NQKV);
    transpose_convert<<<dim3(NQKV / 32, D_MODEL / 32), dim3(32, 8), 0, stream>>>(wql, WqlT, D_MODEL, NQKV);
    transpose_convert<<<dim3(D_MODEL / 32, D_MODEL / 32), dim3(32, 8), 0, stream>>>(wdv, WdvT, D_MODEL, D_MODEL);
    transpose_convert<<<dim3(D_MODEL / 32, D_MODEL / 32), dim3(32, 8), 0, stream>>>(wdl, WdlT, D_MODEL, D_MODEL);
    mask_scan<<<1, 256, 0, stream>>>(tt, lists, counts);
    gemm_expert<u16><<<dim3(NQKV / 256, 8, 2), 512, 0, stream>>>(Abf, WqvT, WqlT, QKV, lists, counts, NQKV);
    rope_kernel<<<BL * NH * 64 / 256, 256, 0, stream>>>(QKV, pos);
    attn_kernel<<<dim3(16, NH, 2), 256, 0, stream>>>(QKV, CTX);
    gemm_expert<float><<<dim3(D_MODEL / 256, 8, 2), 512, 0, stream>>>(CTX, WdvT, WdlT, out, lists, counts, D_MODEL);
}